// Round 9
// baseline (592.572 us; speedup 1.0000x reference)
//
#include <hip/hip_runtime.h>
#include <hip/hip_bf16.h>
#include <stdint.h>

typedef __bf16 bf16;
typedef __bf16 bf16x8 __attribute__((ext_vector_type(8)));
typedef __bf16 bf16x4 __attribute__((ext_vector_type(4)));
typedef float f32x4 __attribute__((ext_vector_type(4)));
typedef unsigned short u16;

__device__ __forceinline__ float b2f(bf16 v) { return (float)v; }
__device__ __forceinline__ bf16 f2b(float f) { return (bf16)f; }

// async global->LDS DMA, 16B per lane. LDS dest must be wave-uniform base +
// lane*16 (lane-linear).
#define GLD16(gp, lp)                                              \
  __builtin_amdgcn_global_load_lds(                                \
      (const __attribute__((address_space(1))) void*)(gp),         \
      (__attribute__((address_space(3))) void*)(lp), 16, 0, 0)

// read element i of a buffer whose dtype is fp32 (isf32=1) or bf16 (isf32=0)
__device__ __forceinline__ float ldval(const void* p, size_t i, int isf32) {
  return isf32 ? ((const float*)p)[i] : b2f(((const bf16*)p)[i]);
}

// ---------------------------------------------------------------------------
// Dtype sniff: bf16 N(0,1) data has exponent field <=129; fp32 buffers read
// as u16 halves contain ~uniform exponent fields (>=135 w.p. ~0.47 each).
// ---------------------------------------------------------------------------
__global__ void sniff_kernel(const void* x, int* flag) {
  __shared__ int smax[256];
  int tid = threadIdx.x;
  const u16* p = (const u16*)x;
  int mx = 0;
  for (int i = tid; i < 8192; i += 256) {
    int e = (p[i] >> 7) & 0xFF;
    mx = mx > e ? mx : e;
  }
  smax[tid] = mx;
  __syncthreads();
  for (int s = 128; s > 0; s >>= 1) {
    if (tid < s) smax[tid] = smax[tid] > smax[tid + s] ? smax[tid] : smax[tid + s];
    __syncthreads();
  }
  if (tid == 0) *flag = (smax[0] >= 135) ? 1 : 0;
}

// vectorized x-convert: 8 elements per thread (16B stores)
__global__ void cvt_kernel8(const void* __restrict__ in, bf16* __restrict__ out,
                            int n8, const int* __restrict__ flag) {
  int f = *flag;
  int i = blockIdx.x * 256 + threadIdx.x;
  if (i >= n8) return;
  bf16x8 o;
  if (f) {
    const float4* p = (const float4*)in + (size_t)i * 2;
    float4 a = p[0], c = p[1];
    o[0] = f2b(a.x); o[1] = f2b(a.y); o[2] = f2b(a.z); o[3] = f2b(a.w);
    o[4] = f2b(c.x); o[5] = f2b(c.y); o[6] = f2b(c.z); o[7] = f2b(c.w);
  } else {
    o = ((const bf16x8*)in)[i];
  }
  ((bf16x8*)out)[i] = o;
}

// ---------------------------------------------------------------------------
// Fused small-vector convert: all 10 bias/gamma/beta vectors in ONE launch.
// ---------------------------------------------------------------------------
__global__ void cvt_biases_kernel(const void* bq, const void* bk, const void* bv,
                                  const void* bo, const void* b1, const void* b2,
                                  const void* g1, const void* be1, const void* g2,
                                  const void* be2, bf16* __restrict__ sv,
                                  const int* __restrict__ flag) {
  int f = *flag;
  int i = blockIdx.x * 256 + threadIdx.x;
  if (i >= 13312) return;
  int seg = i >> 10;
  int off = i & 1023;
  const void* src;
  switch (seg) {
    case 0: src = bq; break;
    case 1: src = bk; break;
    case 2: src = bv; break;
    case 3: src = bo; break;
    case 4: case 5: case 6: case 7: src = b1; off = i - 4096; break;
    case 8: src = b2; break;
    case 9: src = g1; break;
    case 10: src = be1; break;
    case 11: src = g2; break;
    default: src = be2; break;
  }
  sv[i] = f2b(ldval(src, off, f));
}

// ---------------------------------------------------------------------------
// Fused weight transpose + convert: all 6 weights in ONE launch.
// ---------------------------------------------------------------------------
__global__ void transpose_all(const void* Wq, const void* Wk, const void* Wv,
                              const void* Wo, const void* W1, const void* W2,
                              bf16* WqkvT, bf16* WoT, bf16* W1T, bf16* W2T,
                              const int* __restrict__ flag) {
  int f = *flag;
  __shared__ bf16 tile[32][33];
  int blk = blockIdx.x;
  const void* in; bf16* out; int K, N, bx, by;
  if (blk < 4096) {
    int w = blk >> 10, t = blk & 1023;
    bx = t & 31; by = t >> 5; K = 1024; N = 1024;
    if (w == 0)      { in = Wq; out = WqkvT; }
    else if (w == 1) { in = Wk; out = WqkvT + 1024 * 1024; }
    else if (w == 2) { in = Wv; out = WqkvT + 2048 * 1024; }
    else             { in = Wo; out = WoT; }
  } else if (blk < 8192) {
    int t = blk - 4096; bx = t & 127; by = t >> 7; K = 1024; N = 4096;
    in = W1; out = W1T;
  } else {
    int t = blk - 8192; bx = t & 31; by = t >> 5; K = 4096; N = 1024;
    in = W2; out = W2T;
  }
  int bn = bx * 32, bk = by * 32;
  int tx = threadIdx.x, ty = threadIdx.y;
#pragma unroll
  for (int i = 0; i < 32; i += 8)
    tile[ty + i][tx] = f2b(ldval(in, (size_t)(bk + ty + i) * N + bn + tx, f));
  __syncthreads();
#pragma unroll
  for (int i = 0; i < 32; i += 8)
    out[(size_t)(bn + ty + i) * K + bk + tx] = tile[tx][ty + i];
}

// ---------------------------------------------------------------------------
// GEMM (B-transposed): C[M,N] = A[M,K] @ Bt[N,K]^T + bias, opt ReLU.
// m97 structure: 128x128 tile, BK=64, LINEAR LDS [128][64], single-buffered
// async global_load_lds staging, 2 barriers per K-step.
// Epilogue buffer Cs ALIASES As (dead after K-loop) -> LDS = 32 KB.
// launch_bounds(256,4): VGPR budget 128 -> natural ~76, no spill; 4 blk/CU.
// ---------------------------------------------------------------------------
template <int ACT, int GROUP>
__global__ __launch_bounds__(256, 4)
void gemm_bt(const bf16* __restrict__ A, const bf16* __restrict__ Bt,
             const bf16* __restrict__ bias, bf16* __restrict__ C,
             int M, int N, int K) {
  __shared__ __attribute__((aligned(16))) bf16 As[128][64];
  __shared__ __attribute__((aligned(16))) bf16 Bs[128][64];
  bf16 (*Cs)[136] = (bf16(*)[136])&As[0][0];  // alias: 8.5 KB < 16 KB
  const int tid = threadIdx.x;
  const int wave = tid >> 6;
  const int lane = tid & 63;

  // XCD-aware swizzle
  const int grid_n = N >> 7;
  const int pid = blockIdx.x;
  const int xcd = pid & 7;
  const int j = pid >> 3;
  const int per = GROUP * grid_n;
  const int chunk = j / per;
  const int r0 = j - chunk * per;
  const int mb = xcd * 8 + chunk * GROUP + (r0 & (GROUP - 1));
  const int nb = r0 / GROUP;
  const int m0 = mb * 128;
  const int n0 = nb * 128;

  const int wr = (wave >> 1) * 64;
  const int wc = (wave & 1) * 64;
  const int row_q = lane & 15;
  const int quad = lane >> 4;

  const f32x4 fz = {0.f, 0.f, 0.f, 0.f};
  f32x4 acc[4][4];
#pragma unroll
  for (int i = 0; i < 4; i++)
#pragma unroll
    for (int jj = 0; jj < 4; jj++) acc[i][jj] = fz;

  int srow[4], sck[4];
#pragma unroll
  for (int i = 0; i < 4; i++) {
    int c = i * 256 + tid;
    srow[i] = c >> 3;
    sck[i] = (c & 7) * 8;
  }

  for (int k0 = 0; k0 < K; k0 += 64) {
    __syncthreads();
#pragma unroll
    for (int i = 0; i < 4; i++) {
      GLD16(A + (size_t)(m0 + srow[i]) * K + k0 + sck[i], &As[srow[i]][sck[i]]);
      GLD16(Bt + (size_t)(n0 + srow[i]) * K + k0 + sck[i], &Bs[srow[i]][sck[i]]);
    }
    __syncthreads();
#pragma unroll
    for (int ks = 0; ks < 2; ks++) {
      bf16x8 af[4], bfr[4];
      int cf = ks * 4 + quad;
#pragma unroll
      for (int mi = 0; mi < 4; mi++)
        af[mi] = *(const bf16x8*)&As[wr + mi * 16 + row_q][cf * 8];
#pragma unroll
      for (int ni = 0; ni < 4; ni++)
        bfr[ni] = *(const bf16x8*)&Bs[wc + ni * 16 + row_q][cf * 8];
#pragma unroll
      for (int mi = 0; mi < 4; mi++)
#pragma unroll
        for (int ni = 0; ni < 4; ni++)
          acc[mi][ni] = __builtin_amdgcn_mfma_f32_16x16x32_bf16(
              af[mi], bfr[ni], acc[mi][ni], 0, 0, 0);
    }
  }

  // epilogue: 4 phases of 32 rows (Cs overlays As; barriers order reuse)
#pragma unroll
  for (int p = 0; p < 4; p++) {
    __syncthreads();
    if ((wave >> 1) == (p >> 1)) {
#pragma unroll
      for (int ni = 0; ni < 4; ni++) {
        int col = wc + ni * 16 + row_q;
        float bval = b2f(bias[n0 + col]);
#pragma unroll
        for (int mi2 = 0; mi2 < 2; mi2++) {
          int mi = (p & 1) * 2 + mi2;
#pragma unroll
          for (int reg = 0; reg < 4; reg++) {
            int lr = mi2 * 16 + quad * 4 + reg;  // 0..31
            float v = acc[mi][ni][reg] + bval;
            if (ACT == 1) v = v > 0.f ? v : 0.f;
            Cs[lr][col] = f2b(v);
          }
        }
      }
    }
    __syncthreads();
#pragma unroll
    for (int i = 0; i < 2; i++) {
      int u = i * 256 + tid;    // 0..511
      int row = u >> 4;         // 0..31
      int cu = u & 15;
      uint4 v = *(const uint4*)&Cs[row][cu * 8];
      *(uint4*)&C[(size_t)(m0 + p * 32 + row) * N + n0 + cu * 8] = v;
    }
  }
}

// ---------------------------------------------------------------------------
// Merged QKV projection: one launch over N=3072 (WqkvT rows contiguous,
// bias arena [bq|bk|bv] contiguous).  nb<16 -> Q|K epilogue into QKb
// (row stride 2048); nb>=16 -> transposed V epilogue into Vg (d-major).
// grid = 64 x 24 = 1536 blocks; GROUP=8 XCD swizzle (1536%8==0, bijective).
// ---------------------------------------------------------------------------
template <int GROUP>
__global__ __launch_bounds__(256, 4)
void gemm_qkv(const bf16* __restrict__ A, const bf16* __restrict__ Bt,
              const bf16* __restrict__ bias, bf16* __restrict__ Cqk,
              bf16* __restrict__ Vg, int M, int K) {
  __shared__ __attribute__((aligned(16))) bf16 As[128][64];
  __shared__ __attribute__((aligned(16))) bf16 Bs[128][64];
  bf16 (*Cs)[136] = (bf16(*)[136])&As[0][0];  // epilogue alias
  const int tid = threadIdx.x;
  const int wave = tid >> 6;
  const int lane = tid & 63;

  const int grid_n = 24;               // 3072/128
  const int pid = blockIdx.x;
  const int xcd = pid & 7;
  const int j = pid >> 3;
  const int per = GROUP * grid_n;
  const int chunk = j / per;
  const int r0 = j - chunk * per;
  const int mb = xcd * 8 + chunk * GROUP + (r0 & (GROUP - 1));
  const int nb = r0 / GROUP;
  const int m0 = mb * 128;
  const int n0 = nb * 128;

  const int wr = (wave >> 1) * 64;
  const int wc = (wave & 1) * 64;
  const int row_q = lane & 15;
  const int quad = lane >> 4;

  const f32x4 fz = {0.f, 0.f, 0.f, 0.f};
  f32x4 acc[4][4];
#pragma unroll
  for (int i = 0; i < 4; i++)
#pragma unroll
    for (int jj = 0; jj < 4; jj++) acc[i][jj] = fz;

  int srow[4], sck[4];
#pragma unroll
  for (int i = 0; i < 4; i++) {
    int c = i * 256 + tid;
    srow[i] = c >> 3;
    sck[i] = (c & 7) * 8;
  }

  for (int k0 = 0; k0 < K; k0 += 64) {
    __syncthreads();
#pragma unroll
    for (int i = 0; i < 4; i++) {
      GLD16(A + (size_t)(m0 + srow[i]) * K + k0 + sck[i], &As[srow[i]][sck[i]]);
      GLD16(Bt + (size_t)(n0 + srow[i]) * K + k0 + sck[i], &Bs[srow[i]][sck[i]]);
    }
    __syncthreads();
#pragma unroll
    for (int ks = 0; ks < 2; ks++) {
      bf16x8 af[4], bfr[4];
      int cf = ks * 4 + quad;
#pragma unroll
      for (int mi = 0; mi < 4; mi++)
        af[mi] = *(const bf16x8*)&As[wr + mi * 16 + row_q][cf * 8];
#pragma unroll
      for (int ni = 0; ni < 4; ni++)
        bfr[ni] = *(const bf16x8*)&Bs[wc + ni * 16 + row_q][cf * 8];
#pragma unroll
      for (int mi = 0; mi < 4; mi++)
#pragma unroll
        for (int ni = 0; ni < 4; ni++)
          acc[mi][ni] = __builtin_amdgcn_mfma_f32_16x16x32_bf16(
              af[mi], bfr[ni], acc[mi][ni], 0, 0, 0);
    }
  }

  if (nb < 16) {
    // Q|K epilogue -> QKb [8192][2048]
#pragma unroll
    for (int p = 0; p < 4; p++) {
      __syncthreads();
      if ((wave >> 1) == (p >> 1)) {
#pragma unroll
        for (int ni = 0; ni < 4; ni++) {
          int col = wc + ni * 16 + row_q;
          float bval = b2f(bias[n0 + col]);
#pragma unroll
          for (int mi2 = 0; mi2 < 2; mi2++) {
            int mi = (p & 1) * 2 + mi2;
#pragma unroll
            for (int reg = 0; reg < 4; reg++) {
              int lr = mi2 * 16 + quad * 4 + reg;
              Cs[lr][col] = f2b(acc[mi][ni][reg] + bval);
            }
          }
        }
      }
      __syncthreads();
#pragma unroll
      for (int i = 0; i < 2; i++) {
        int u = i * 256 + tid;
        int row = u >> 4;
        int cu = u & 15;
        uint4 v = *(const uint4*)&Cs[row][cu * 8];
        *(uint4*)&Cqk[(size_t)(m0 + p * 32 + row) * 2048 + n0 + cu * 8] = v;
      }
    }
  } else {
    // V epilogue (transposed) -> Vg[b*1024 + dcol][s]
    const int n0v = n0 - 2048;       // 0..896
    const int b = m0 >> 11;
    const int s0 = m0 & 2047;
#pragma unroll
    for (int p = 0; p < 4; p++) {
      __syncthreads();
      if ((wave & 1) == (p >> 1)) {
#pragma unroll
        for (int ni2 = 0; ni2 < 2; ni2++) {
          int ni = (p & 1) * 2 + ni2;
          int cl = ni2 * 16 + row_q;
          float bval = b2f(bias[n0 + p * 32 + cl]);
#pragma unroll
          for (int mi = 0; mi < 4; mi++)
#pragma unroll
            for (int reg = 0; reg < 4; reg++) {
              int row = wr + mi * 16 + quad * 4 + reg;
              Cs[cl][row] = f2b(acc[mi][ni][reg] + bval);
            }
        }
      }
      __syncthreads();
#pragma unroll
      for (int i = 0; i < 2; i++) {
        int u = i * 256 + tid;
        int cl = u >> 4;
        int rc = u & 15;
        uint4 v = *(const uint4*)&Cs[cl][rc * 8];
        *(uint4*)&Vg[(size_t)(b * 1024 + n0v + p * 32 + cl) * 2048 + s0 + rc * 8] = v;
      }
    }
  }
}

// ---------------------------------------------------------------------------
// Flash attention, swapped-QK^T softmax + async GLD16 staging.
// BC=64 (was 128): LDS 25.6 KB (Ks 8K + Vt 8K + Ps 9.2K) -> 6 blocks/CU
// (was 3 at 50 KB).  Same total exp/MFMA/byte counts (32 tiles x half work);
// the doubled TLP overlaps the per-tile staging drains that were ~30% of
// cycles at 3 blocks/CU.  sacc[8]->sacc[4] drops VGPR so (256,6) (cap ~85)
// does not squeeze (round-6 tripwire).
// ---------------------------------------------------------------------------
#define BC 64
__global__ __launch_bounds__(256, 6)
void attn_kernel(const bf16* __restrict__ QKb, const bf16* __restrict__ Vg,
                 const int* __restrict__ mask, bf16* __restrict__ O) {
  __shared__ __attribute__((aligned(16))) bf16 Ks[BC][64];     // [key][d] swz
  __shared__ __attribute__((aligned(16))) bf16 Vt[64][BC];     // [d][key] swz
  __shared__ __attribute__((aligned(16))) bf16 Ps[4][16][72];  // per-wave P
  const int tid = threadIdx.x;
  const int wave = tid >> 6, lane = tid & 63;
  const int pid = blockIdx.x;         // 2048 blocks
  const int xcd = pid & 7;
  const int jj = pid >> 3;            // 0..255
  const int bh = xcd * 8 + (jj >> 5); // 8 bh per XCD
  const int b = bh >> 4, h = bh & 15;
  const int q0 = (jj & 31) * 64;
  const int row_q = lane & 15, quad = lane >> 4;

  bf16x8 qf[2];
  {
    int qrow = q0 + wave * 16 + row_q;
    const bf16* qp = QKb + (size_t)(b * 2048 + qrow) * 2048 + h * 64 + quad * 8;
    qf[0] = *(const bf16x8*)qp;
    qf[1] = *(const bf16x8*)(qp + 32);
#pragma unroll
    for (int ks = 0; ks < 2; ks++)
#pragma unroll
      for (int e = 0; e < 8; e++) qf[ks][e] = f2b(b2f(qf[ks][e]) * 0.125f);
  }
  float m_i = -1e30f, l_i = 0.f;
  const f32x4 fz = {0.f, 0.f, 0.f, 0.f};
  f32x4 o_acc[4];
#pragma unroll
  for (int d = 0; d < 4; d++) o_acc[d] = fz;

  // staging coords (linear LDS dest; XOR-swizzled global source chunk)
  // 512 16B-chunks per tile (K: 64x64, V: 64x64), 2 per thread each.
  int ki[2], kdc[2], ksc[2], vsc[2];
#pragma unroll
  for (int j = 0; j < 2; j++) {
    int c = j * 256 + tid;
    ki[j] = c >> 3;  kdc[j] = c & 7;
    ksc[j] = (c & 7) ^ (ki[j] & 7);
    vsc[j] = ksc[j];   // V uses same (row=d) layout: (c&7)^(row&7)
  }
  const bf16* Kbase = QKb + (size_t)b * 2048 * 2048 + 1024 + h * 64;
  const bf16* Vbase = Vg + (size_t)(b * 1024 + h * 64) * 2048;
  const int* mrow = mask + b * 2048;
  const int swz = row_q & 7;

  // pre-resolve per-tile mask fast-path bits (32 tiles -> u32)
  unsigned int allmask = 0;
  for (int kb = 0; kb < 2048 / BC; kb++) {
    int mm = mrow[kb * BC + lane];
    if (__ballot(mm != 0) == ~0ull) allmask |= (1u << kb);
  }

  for (int kb = 0; kb < 2048 / BC; kb++) {
    __syncthreads();   // previous tile's PV reads done
#pragma unroll
    for (int j = 0; j < 2; j++)
      GLD16(Kbase + (size_t)(kb * BC + ki[j]) * 2048 + ksc[j] * 8,
            &Ks[ki[j]][kdc[j] * 8]);
#pragma unroll
    for (int j = 0; j < 2; j++)
      GLD16(Vbase + (size_t)ki[j] * 2048 + kb * BC + vsc[j] * 8,
            &Vt[ki[j]][kdc[j] * 8]);
    __syncthreads();   // vmcnt(0) drain: tiles resident

    // S^T = K Q^T : lane -> q-row = row_q, keys = nt*16 + quad*4 + r
    f32x4 sacc[4];
#pragma unroll
    for (int nt = 0; nt < 4; nt++) sacc[nt] = fz;
#pragma unroll
    for (int ks = 0; ks < 2; ks++) {
      int kcf = ((ks * 4 + quad) ^ swz) * 8;
#pragma unroll
      for (int nt = 0; nt < 4; nt++) {
        bf16x8 kf = *(const bf16x8*)&Ks[nt * 16 + row_q][kcf];
        sacc[nt] = __builtin_amdgcn_mfma_f32_16x16x32_bf16(kf, qf[ks], sacc[nt], 0, 0, 0);
      }
    }
    if (!((allmask >> kb) & 1u)) {  // rare path: apply mask per key
#pragma unroll
      for (int nt = 0; nt < 4; nt++) {
        int4 m4 = *(const int4*)&mrow[kb * BC + nt * 16 + quad * 4];
#pragma unroll
        for (int r = 0; r < 4; r++)
          if (((const int*)&m4)[r] == 0) sacc[nt][r] = -1e9f;
      }
    }
    // row max: lane-local tree over 16, then reduce across the 4 quads
    float mq[4];
#pragma unroll
    for (int nt = 0; nt < 4; nt++)
      mq[nt] = fmaxf(fmaxf(sacc[nt][0], sacc[nt][1]),
                     fmaxf(sacc[nt][2], sacc[nt][3]));
    float mx = fmaxf(fmaxf(mq[0], mq[1]), fmaxf(mq[2], mq[3]));
    mx = fmaxf(mx, __shfl_xor(mx, 16));
    mx = fmaxf(mx, __shfl_xor(mx, 32));
    // defer-max: skip rescale while max growth <= 5 (P bounded by e^5~148)
    if (!__all(mx - m_i <= 5.0f)) {
      float mnew = fmaxf(m_i, mx);
      float alpha = __expf(m_i - mnew);
      m_i = mnew;
      l_i *= alpha;
      float al[4];
#pragma unroll
      for (int r = 0; r < 4; r++) al[r] = __shfl(alpha, quad * 4 + r);
#pragma unroll
      for (int d = 0; d < 4; d++)
#pragma unroll
        for (int r = 0; r < 4; r++) o_acc[d][r] *= al[r];
    }
    float rs = 0.f;
#pragma unroll
    for (int nt = 0; nt < 4; nt++) {
      float p0 = __expf(sacc[nt][0] - m_i);
      float p1 = __expf(sacc[nt][1] - m_i);
      float p2 = __expf(sacc[nt][2] - m_i);
      float p3 = __expf(sacc[nt][3] - m_i);
      rs += (p0 + p1) + (p2 + p3);
      bf16x4 pv = {f2b(p0), f2b(p1), f2b(p2), f2b(p3)};
      *(bf16x4*)&Ps[wave][row_q][nt * 16 + quad * 4] = pv;  // ds_write_b64
    }
    rs += __shfl_xor(rs, 16);
    rs += __shfl_xor(rs, 32);
    l_i += rs;
    // O += P V  (in-wave ds_write->ds_read ordering handled by compiler)
#pragma unroll
    for (int kst = 0; kst < 2; kst++) {
      bf16x8 pf = *(const bf16x8*)&Ps[wave][row_q][kst * 32 + quad * 8];
      int vcf = ((kst * 4 + quad) ^ swz) * 8;
#pragma unroll
      for (int d = 0; d < 4; d++) {
        bf16x8 vf = *(const bf16x8*)&Vt[d * 16 + row_q][vcf];
        o_acc[d] = __builtin_amdgcn_mfma_f32_16x16x32_bf16(pf, vf, o_acc[d], 0, 0, 0);
      }
    }
  }
  float lv[4];
#pragma unroll
  for (int r = 0; r < 4; r++) lv[r] = __shfl(l_i, quad * 4 + r);
#pragma unroll
  for (int d = 0; d < 4; d++) {
#pragma unroll
    for (int r = 0; r < 4; r++) {
      int row = q0 + wave * 16 + quad * 4 + r;
      float v = o_acc[d][r] / fmaxf(lv[r], 1e-20f);
      O[(size_t)(b * 2048 + row) * 1024 + h * 64 + d * 16 + row_q] = f2b(v);
    }
  }
}

// ---------------------------------------------------------------------------
// Residual + LayerNorm (bf16 out), VECTORIZED: thread t owns elems 4t..4t+3.
// ---------------------------------------------------------------------------
__global__ __launch_bounds__(256)
void ln_kernel(const bf16* __restrict__ a, const bf16* __restrict__ res,
               const bf16* __restrict__ g, const bf16* __restrict__ be,
               bf16* __restrict__ out) {
  const int tid = threadIdx.x;
  __shared__ float red[8];
  const size_t base = (size_t)blockIdx.x * 1024;
  bf16x4 av = *(const bf16x4*)&a[base + tid * 4];
  bf16x4 rv = *(const bf16x4*)&res[base + tid * 4];
  float xs[4], sum = 0.f, sq = 0.f;
#pragma unroll
  for (int i = 0; i < 4; i++) {
    float x = b2f(av[i]) + b2f(rv[i]);
    xs[i] = x; sum += x; sq += x * x;
  }
#pragma unroll
  for (int off = 1; off < 64; off <<= 1) {
    sum += __shfl_xor(sum, off);
    sq += __shfl_xor(sq, off);
  }
  int wave = tid >> 6, lane = tid & 63;
  if (lane == 0) { red[wave] = sum; red[4 + wave] = sq; }
  __syncthreads();
  sum = red[0] + red[1] + red[2] + red[3];
  sq = red[4] + red[5] + red[6] + red[7];
  float mu = sum * (1.f / 1024.f);
  float var = sq * (1.f / 1024.f) - mu * mu;
  float rstd = rsqrtf(fmaxf(var, 0.f) + 1e-5f);
  bf16x4 gv = *(const bf16x4*)&g[tid * 4];
  bf16x4 bv = *(const bf16x4*)&be[tid * 4];
  bf16x4 ov;
#pragma unroll
  for (int i = 0; i < 4; i++)
    ov[i] = f2b((xs[i] - mu) * rstd * b2f(gv[i]) + b2f(bv[i]));
  *(bf16x4*)&out[base + tid * 4] = ov;
}

// Final LN: writes fp32 or bf16 per flag; vectorized.
__global__ __launch_bounds__(256)
void ln_out_kernel(const bf16* __restrict__ a, const bf16* __restrict__ res,
                   const bf16* __restrict__ g, const bf16* __restrict__ be,
                   void* __restrict__ out, const int* __restrict__ flag) {
  const int f = *flag;
  const int tid = threadIdx.x;
  __shared__ float red[8];
  const size_t base = (size_t)blockIdx.x * 1024;
  bf16x4 av = *(const bf16x4*)&a[base + tid * 4];
  bf16x4 rv = *(const bf16x4*)&res[base + tid * 4];
  float xs[4], sum = 0.f, sq = 0.f;
#pragma unroll
  for (int i = 0; i < 4; i++) {
    float x = b2f(av[i]) + b2f(rv[i]);
    xs[i] = x; sum += x; sq += x * x;
  }
#pragma unroll
  for (int off = 1; off < 64; off <<= 1) {
    sum += __shfl_xor(sum, off);
    sq += __shfl_xor(sq, off);
  }
  int wave = tid >> 6, lane = tid & 63;
  if (lane == 0) { red[wave] = sum; red[4 + wave] = sq; }
  __syncthreads();
  sum = red[0] + red[1] + red[2] + red[3];
  sq = red[4] + red[5] + red[6] + red[7];
  float mu = sum * (1.f / 1024.f);
  float var = sq * (1.f / 1024.f) - mu * mu;
  float rstd = rsqrtf(fmaxf(var, 0.f) + 1e-5f);
  bf16x4 gv = *(const bf16x4*)&g[tid * 4];
  bf16x4 bv = *(const bf16x4*)&be[tid * 4];
  float y[4];
#pragma unroll
  for (int i = 0; i < 4; i++)
    y[i] = (xs[i] - mu) * rstd * b2f(gv[i]) + b2f(bv[i]);
  if (f) {
    float4 o = {y[0], y[1], y[2], y[3]};
    ((float4*)out)[base / 4 + tid] = o;
  } else {
    bf16x4 o = {f2b(y[0]), f2b(y[1]), f2b(y[2]), f2b(y[3])};
    *(bf16x4*)&((bf16*)out)[base + tid * 4] = o;
  }
}

// ---------------------------------------------------------------------------
extern "C" void kernel_launch(void* const* d_in, const int* in_sizes, int n_in,
                              void* d_out, int out_size, void* d_ws, size_t ws_size,
                              hipStream_t stream) {
  (void)in_sizes; (void)n_in; (void)out_size; (void)ws_size;
  const void* x   = d_in[0];
  const int* mask = (const int*)d_in[1];
  const void* Wq  = d_in[2];
  const void* bq  = d_in[3];
  const void* Wk  = d_in[4];
  const void* bk  = d_in[5];
  const void* Wv  = d_in[6];
  const void* bv  = d_in[7];
  const void* Wo  = d_in[8];
  const void* bo  = d_in[9];
  const void* W1  = d_in[10];
  const void* b1  = d_in[11];
  const void* W2  = d_in[12];
  const void* b2  = d_in[13];
  const void* g1  = d_in[14];
  const void* be1 = d_in[15];
  const void* g2  = d_in[16];
  const void* be2 = d_in[17];

  // workspace layout (125,861,888 B total)
  char* ws = (char*)d_ws;
  bf16* xb    = (bf16*)(ws + 0);            // 16,777,216  [8192][1024]
  bf16* WqkvT = (bf16*)(ws + 16777216);     //  6,291,456  [3072][1024]
  bf16* WoT   = (bf16*)(ws + 23068672);     //  2,097,152  [1024][1024]
  bf16* W1T   = (bf16*)(ws + 25165824);     //  8,388,608  [4096][1024]
  bf16* W2T   = (bf16*)(ws + 33554432);     //  8,388,608  [1024][4096]
  bf16* sv    = (bf16*)(ws + 41943040);     // small-vector arena
  bf16* bqkvB = sv;                         // 3072
  bf16* boB   = sv + 3072;                  // 1024
  bf16* b1B   = sv + 4096;                  // 4096
  bf16* b2B   = sv + 8192;                  // 1024
  bf16* g1B   = sv + 9216;                  // 1024
  bf16* be1B  = sv + 10240;                 // 1024
  bf16* g2B   = sv + 11264;                 // 1024
  bf16* be2B  = sv + 12288;                 // 1024
  int*  flag  = (int*)(ws + 41943040 + 26624);
  bf16* QKb   = (bf16*)(ws + 41975808);     // 33,554,432  [8192][2048]
  bf16* Vg    = (bf16*)(ws + 75530240);     // 16,777,216  [4096][2048] d-major
  bf16* Obuf  = (bf16*)(ws + 92307456);     // 16,777,216  [8192][1024]
  bf16* hbuf  = (bf16*)(ws + 109084672);    // 16,777,216  [8192][1024]
  bf16* attnp = (bf16*)(ws + 41975808);     // reuses QKb (dead after attn)
  bf16* ff1   = (bf16*)(ws + 41975808);     // 67,108,864  reuses QKb+Vg+Obuf
  bf16* ff2o  = (bf16*)(ws + 0);            // reuses xb (dead after LN1)

  sniff_kernel<<<1, 256, 0, stream>>>(x, flag);

  cvt_kernel8<<<4096, 256, 0, stream>>>(x, xb, 1048576, flag);
  cvt_biases_kernel<<<52, 256, 0, stream>>>(bq, bk, bv, bo, b1, b2, g1, be1,
                                            g2, be2, sv, flag);

  dim3 tb(32, 8);
  transpose_all<<<12288, tb, 0, stream>>>(Wq, Wk, Wv, Wo, W1, W2,
                                          WqkvT, WoT, W1T, W2T, flag);

  // merged QKV projection (N=3072; Q|K -> QKb, V -> Vg transposed)
  gemm_qkv<8><<<1536, 256, 0, stream>>>(xb, WqkvT, bqkvB, QKb, Vg, 8192, 1024);
  attn_kernel<<<2048, 256, 0, stream>>>(QKb, Vg, mask, Obuf);
  gemm_bt<0, 8><<<512, 256, 0, stream>>>(Obuf, WoT, boB, attnp, 8192, 1024, 1024);
  ln_kernel<<<8192, 256, 0, stream>>>(xb, attnp, g1B, be1B, hbuf);
  gemm_bt<1, 8><<<2048, 256, 0, stream>>>(hbuf, W1T, b1B, ff1, 8192, 4096, 1024);
  gemm_bt<0, 4><<<512, 256, 0, stream>>>(ff1, W2T, b2B, ff2o, 8192, 1024, 4096);
  ln_out_kernel<<<8192, 256, 0, stream>>>(hbuf, ff2o, g2B, be2B, d_out, flag);
}

// Round 10
// 564.184 us; speedup vs baseline: 1.0503x; 1.0503x over previous
//
#include <hip/hip_runtime.h>
#include <hip/hip_bf16.h>
#include <stdint.h>

typedef __bf16 bf16;
typedef __bf16 bf16x8 __attribute__((ext_vector_type(8)));
typedef __bf16 bf16x4 __attribute__((ext_vector_type(4)));
typedef float f32x4 __attribute__((ext_vector_type(4)));
typedef unsigned short u16;

__device__ __forceinline__ float b2f(bf16 v) { return (float)v; }
__device__ __forceinline__ bf16 f2b(float f) { return (bf16)f; }

// async global->LDS DMA, 16B per lane. LDS dest must be wave-uniform base +
// lane*16 (lane-linear).
#define GLD16(gp, lp)                                              \
  __builtin_amdgcn_global_load_lds(                                \
      (const __attribute__((address_space(1))) void*)(gp),         \
      (__attribute__((address_space(3))) void*)(lp), 16, 0, 0)

// read element i of a buffer whose dtype is fp32 (isf32=1) or bf16 (isf32=0)
__device__ __forceinline__ float ldval(const void* p, size_t i, int isf32) {
  return isf32 ? ((const float*)p)[i] : b2f(((const bf16*)p)[i]);
}

// ---------------------------------------------------------------------------
// Dtype sniff
// ---------------------------------------------------------------------------
__global__ void sniff_kernel(const void* x, int* flag) {
  __shared__ int smax[256];
  int tid = threadIdx.x;
  const u16* p = (const u16*)x;
  int mx = 0;
  for (int i = tid; i < 8192; i += 256) {
    int e = (p[i] >> 7) & 0xFF;
    mx = mx > e ? mx : e;
  }
  smax[tid] = mx;
  __syncthreads();
  for (int s = 128; s > 0; s >>= 1) {
    if (tid < s) smax[tid] = smax[tid] > smax[tid + s] ? smax[tid] : smax[tid + s];
    __syncthreads();
  }
  if (tid == 0) *flag = (smax[0] >= 135) ? 1 : 0;
}

// vectorized x-convert: 8 elements per thread (16B stores)
__global__ void cvt_kernel8(const void* __restrict__ in, bf16* __restrict__ out,
                            int n8, const int* __restrict__ flag) {
  int f = *flag;
  int i = blockIdx.x * 256 + threadIdx.x;
  if (i >= n8) return;
  bf16x8 o;
  if (f) {
    const float4* p = (const float4*)in + (size_t)i * 2;
    float4 a = p[0], c = p[1];
    o[0] = f2b(a.x); o[1] = f2b(a.y); o[2] = f2b(a.z); o[3] = f2b(a.w);
    o[4] = f2b(c.x); o[5] = f2b(c.y); o[6] = f2b(c.z); o[7] = f2b(c.w);
  } else {
    o = ((const bf16x8*)in)[i];
  }
  ((bf16x8*)out)[i] = o;
}

// ---------------------------------------------------------------------------
// Fused small-vector convert
// ---------------------------------------------------------------------------
__global__ void cvt_biases_kernel(const void* bq, const void* bk, const void* bv,
                                  const void* bo, const void* b1, const void* b2,
                                  const void* g1, const void* be1, const void* g2,
                                  const void* be2, bf16* __restrict__ sv,
                                  const int* __restrict__ flag) {
  int f = *flag;
  int i = blockIdx.x * 256 + threadIdx.x;
  if (i >= 13312) return;
  int seg = i >> 10;
  int off = i & 1023;
  const void* src;
  switch (seg) {
    case 0: src = bq; break;
    case 1: src = bk; break;
    case 2: src = bv; break;
    case 3: src = bo; break;
    case 4: case 5: case 6: case 7: src = b1; off = i - 4096; break;
    case 8: src = b2; break;
    case 9: src = g1; break;
    case 10: src = be1; break;
    case 11: src = g2; break;
    default: src = be2; break;
  }
  sv[i] = f2b(ldval(src, off, f));
}

// ---------------------------------------------------------------------------
// Fused weight transpose + convert
// ---------------------------------------------------------------------------
__global__ void transpose_all(const void* Wq, const void* Wk, const void* Wv,
                              const void* Wo, const void* W1, const void* W2,
                              bf16* WqkvT, bf16* WoT, bf16* W1T, bf16* W2T,
                              const int* __restrict__ flag) {
  int f = *flag;
  __shared__ bf16 tile[32][33];
  int blk = blockIdx.x;
  const void* in; bf16* out; int K, N, bx, by;
  if (blk < 4096) {
    int w = blk >> 10, t = blk & 1023;
    bx = t & 31; by = t >> 5; K = 1024; N = 1024;
    if (w == 0)      { in = Wq; out = WqkvT; }
    else if (w == 1) { in = Wk; out = WqkvT + 1024 * 1024; }
    else if (w == 2) { in = Wv; out = WqkvT + 2048 * 1024; }
    else             { in = Wo; out = WoT; }
  } else if (blk < 8192) {
    int t = blk - 4096; bx = t & 127; by = t >> 7; K = 1024; N = 4096;
    in = W1; out = W1T;
  } else {
    int t = blk - 8192; bx = t & 31; by = t >> 5; K = 4096; N = 1024;
    in = W2; out = W2T;
  }
  int bn = bx * 32, bk = by * 32;
  int tx = threadIdx.x, ty = threadIdx.y;
#pragma unroll
  for (int i = 0; i < 32; i += 8)
    tile[ty + i][tx] = f2b(ldval(in, (size_t)(bk + ty + i) * N + bn + tx, f));
  __syncthreads();
#pragma unroll
  for (int i = 0; i < 32; i += 8)
    out[(size_t)(bn + ty + i) * K + bk + tx] = tile[tx][ty + i];
}

// ---------------------------------------------------------------------------
// Pipelined GEMM main loop (3-slot, BK=32, counted vmcnt -- T4):
//   prologue stages tiles 0,1,2; per iteration: [barrier] 8 ds_read + 16 MFMA
//   [barrier] stage tile t+3 into slot t%3, then s_waitcnt vmcnt(8/4/0).
// Slot reuse distance 3 => the stage write lands during 2 iterations where
// nobody reads that slot.  Own-vmcnt + barrier => cross-thread residency.
// Raw s_barrier (no vmcnt(0) drain) is the whole point; never drain in loop.
// LDS = 3*(8+8) KB = 48 KB (+ aliased epilogue) -> 3 blocks/CU retained.
// Read swizzle: chunk ^= (row>>1)&3 on BOTH global source and LDS read ->
// 2-way bank phasing (free).
// ---------------------------------------------------------------------------
#define GEMM_PIPE_LOOP(Aptr, Bptr)                                             \
  const int NT = K >> 5;                                                       \
  int srow[2], sch[2], ssc[2];                                                 \
  _Pragma("unroll")                                                            \
  for (int j = 0; j < 2; ++j) {                                                \
    int c = j * 256 + tid;                                                     \
    srow[j] = c >> 2;                                                          \
    sch[j] = (c & 3) * 8;                                                      \
    ssc[j] = ((c & 3) ^ ((srow[j] >> 1) & 3)) * 8;                             \
  }                                                                            \
  const bf16* pA0 = Aptr + (size_t)(m0 + srow[0]) * K + ssc[0];                \
  const bf16* pA1 = Aptr + (size_t)(m0 + srow[1]) * K + ssc[1];                \
  const bf16* pB0 = Bptr + (size_t)(n0 + srow[0]) * K + ssc[0];                \
  const bf16* pB1 = Bptr + (size_t)(n0 + srow[1]) * K + ssc[1];                \
  _Pragma("unroll")                                                            \
  for (int tt = 0; tt < 3; ++tt) {                                             \
    GLD16(pA0 + tt * 32, &As[tt][srow[0]][sch[0]]);                            \
    GLD16(pB0 + tt * 32, &Bs[tt][srow[0]][sch[0]]);                            \
    GLD16(pA1 + tt * 32, &As[tt][srow[1]][sch[1]]);                            \
    GLD16(pB1 + tt * 32, &Bs[tt][srow[1]][sch[1]]);                            \
  }                                                                            \
  asm volatile("s_waitcnt vmcnt(8)" ::: "memory");                             \
  const int cf = (quad ^ ((row_q >> 1) & 3)) * 8;                              \
  int slot = 0;                                                                \
  for (int t = 0; t < NT; ++t) {                                               \
    __builtin_amdgcn_s_barrier();                                              \
    bf16x8 af[4], bfr[4];                                                      \
    _Pragma("unroll")                                                          \
    for (int mi = 0; mi < 4; mi++)                                             \
      af[mi] = *(const bf16x8*)&As[slot][wr + mi * 16 + row_q][cf];            \
    _Pragma("unroll")                                                          \
    for (int ni = 0; ni < 4; ni++)                                             \
      bfr[ni] = *(const bf16x8*)&Bs[slot][wc + ni * 16 + row_q][cf];           \
    _Pragma("unroll")                                                          \
    for (int mi = 0; mi < 4; mi++)                                             \
      _Pragma("unroll")                                                        \
      for (int ni = 0; ni < 4; ni++)                                           \
        acc[mi][ni] = __builtin_amdgcn_mfma_f32_16x16x32_bf16(                 \
            af[mi], bfr[ni], acc[mi][ni], 0, 0, 0);                            \
    __builtin_amdgcn_s_barrier();                                              \
    __builtin_amdgcn_sched_barrier(0);  /* keep stages below the barrier */    \
    if (t + 3 < NT) {                                                          \
      int k0 = (t + 3) << 5;                                                   \
      GLD16(pA0 + k0, &As[slot][srow[0]][sch[0]]);                             \
      GLD16(pB0 + k0, &Bs[slot][srow[0]][sch[0]]);                             \
      GLD16(pA1 + k0, &As[slot][srow[1]][sch[1]]);                             \
      GLD16(pB1 + k0, &Bs[slot][srow[1]][sch[1]]);                             \
    }                                                                          \
    int rem = NT - 1 - t;                                                      \
    if (rem >= 3)      asm volatile("s_waitcnt vmcnt(8)" ::: "memory");        \
    else if (rem == 2) asm volatile("s_waitcnt vmcnt(4)" ::: "memory");        \
    else if (rem == 1) asm volatile("s_waitcnt vmcnt(0)" ::: "memory");        \
    slot = (slot == 2) ? 0 : slot + 1;                                         \
  }

// ---------------------------------------------------------------------------
// GEMM (B-transposed): C[M,N] = A[M,K] @ Bt[N,K]^T + bias, opt ReLU.
// ---------------------------------------------------------------------------
template <int ACT, int GROUP>
__global__ __launch_bounds__(256, 3)
void gemm_bt(const bf16* __restrict__ A, const bf16* __restrict__ Bt,
             const bf16* __restrict__ bias, bf16* __restrict__ C,
             int M, int N, int K) {
  __shared__ __attribute__((aligned(16))) bf16 As[3][128][32];
  __shared__ __attribute__((aligned(16))) bf16 Bs[3][128][32];
  bf16 (*Cs)[136] = (bf16(*)[136])&As[0][0][0];  // epilogue alias (8.5 KB)
  const int tid = threadIdx.x;
  const int wave = tid >> 6;
  const int lane = tid & 63;

  // XCD-aware swizzle
  const int grid_n = N >> 7;
  const int pid = blockIdx.x;
  const int xcd = pid & 7;
  const int j = pid >> 3;
  const int per = GROUP * grid_n;
  const int chunk = j / per;
  const int r0 = j - chunk * per;
  const int mb = xcd * 8 + chunk * GROUP + (r0 & (GROUP - 1));
  const int nb = r0 / GROUP;
  const int m0 = mb * 128;
  const int n0 = nb * 128;

  const int wr = (wave >> 1) * 64;
  const int wc = (wave & 1) * 64;
  const int row_q = lane & 15;
  const int quad = lane >> 4;

  const f32x4 fz = {0.f, 0.f, 0.f, 0.f};
  f32x4 acc[4][4];
#pragma unroll
  for (int i = 0; i < 4; i++)
#pragma unroll
    for (int jj = 0; jj < 4; jj++) acc[i][jj] = fz;

  GEMM_PIPE_LOOP(A, Bt)

  // epilogue: 4 phases of 32 rows (Cs overlays As; __syncthreads drains)
#pragma unroll
  for (int p = 0; p < 4; p++) {
    __syncthreads();
    if ((wave >> 1) == (p >> 1)) {
#pragma unroll
      for (int ni = 0; ni < 4; ni++) {
        int col = wc + ni * 16 + row_q;
        float bval = b2f(bias[n0 + col]);
#pragma unroll
        for (int mi2 = 0; mi2 < 2; mi2++) {
          int mi = (p & 1) * 2 + mi2;
#pragma unroll
          for (int reg = 0; reg < 4; reg++) {
            int lr = mi2 * 16 + quad * 4 + reg;  // 0..31
            float v = acc[mi][ni][reg] + bval;
            if (ACT == 1) v = v > 0.f ? v : 0.f;
            Cs[lr][col] = f2b(v);
          }
        }
      }
    }
    __syncthreads();
#pragma unroll
    for (int i = 0; i < 2; i++) {
      int u = i * 256 + tid;    // 0..511
      int row = u >> 4;         // 0..31
      int cu = u & 15;
      uint4 v = *(const uint4*)&Cs[row][cu * 8];
      *(uint4*)&C[(size_t)(m0 + p * 32 + row) * N + n0 + cu * 8] = v;
    }
  }
}

// ---------------------------------------------------------------------------
// Merged QKV projection (pipelined main loop, dual epilogue).
// ---------------------------------------------------------------------------
template <int GROUP>
__global__ __launch_bounds__(256, 3)
void gemm_qkv(const bf16* __restrict__ A, const bf16* __restrict__ Bt,
              const bf16* __restrict__ bias, bf16* __restrict__ Cqk,
              bf16* __restrict__ Vg, int M, int K) {
  __shared__ __attribute__((aligned(16))) bf16 As[3][128][32];
  __shared__ __attribute__((aligned(16))) bf16 Bs[3][128][32];
  bf16 (*Cs)[136] = (bf16(*)[136])&As[0][0][0];
  const int tid = threadIdx.x;
  const int wave = tid >> 6;
  const int lane = tid & 63;

  const int grid_n = 24;               // 3072/128
  const int pid = blockIdx.x;
  const int xcd = pid & 7;
  const int j = pid >> 3;
  const int per = GROUP * grid_n;
  const int chunk = j / per;
  const int r0 = j - chunk * per;
  const int mb = xcd * 8 + chunk * GROUP + (r0 & (GROUP - 1));
  const int nb = r0 / GROUP;
  const int m0 = mb * 128;
  const int n0 = nb * 128;

  const int wr = (wave >> 1) * 64;
  const int wc = (wave & 1) * 64;
  const int row_q = lane & 15;
  const int quad = lane >> 4;

  const f32x4 fz = {0.f, 0.f, 0.f, 0.f};
  f32x4 acc[4][4];
#pragma unroll
  for (int i = 0; i < 4; i++)
#pragma unroll
    for (int jj = 0; jj < 4; jj++) acc[i][jj] = fz;

  GEMM_PIPE_LOOP(A, Bt)

  if (nb < 16) {
    // Q|K epilogue -> QKb [8192][2048]
#pragma unroll
    for (int p = 0; p < 4; p++) {
      __syncthreads();
      if ((wave >> 1) == (p >> 1)) {
#pragma unroll
        for (int ni = 0; ni < 4; ni++) {
          int col = wc + ni * 16 + row_q;
          float bval = b2f(bias[n0 + col]);
#pragma unroll
          for (int mi2 = 0; mi2 < 2; mi2++) {
            int mi = (p & 1) * 2 + mi2;
#pragma unroll
            for (int reg = 0; reg < 4; reg++) {
              int lr = mi2 * 16 + quad * 4 + reg;
              Cs[lr][col] = f2b(acc[mi][ni][reg] + bval);
            }
          }
        }
      }
      __syncthreads();
#pragma unroll
      for (int i = 0; i < 2; i++) {
        int u = i * 256 + tid;
        int row = u >> 4;
        int cu = u & 15;
        uint4 v = *(const uint4*)&Cs[row][cu * 8];
        *(uint4*)&Cqk[(size_t)(m0 + p * 32 + row) * 2048 + n0 + cu * 8] = v;
      }
    }
  } else {
    // V epilogue (transposed) -> Vg[b*1024 + dcol][s]
    const int n0v = n0 - 2048;       // 0..896
    const int b = m0 >> 11;
    const int s0 = m0 & 2047;
#pragma unroll
    for (int p = 0; p < 4; p++) {
      __syncthreads();
      if ((wave & 1) == (p >> 1)) {
#pragma unroll
        for (int ni2 = 0; ni2 < 2; ni2++) {
          int ni = (p & 1) * 2 + ni2;
          int cl = ni2 * 16 + row_q;
          float bval = b2f(bias[n0 + p * 32 + cl]);
#pragma unroll
          for (int mi = 0; mi < 4; mi++)
#pragma unroll
            for (int reg = 0; reg < 4; reg++) {
              int row = wr + mi * 16 + quad * 4 + reg;
              Cs[cl][row] = f2b(acc[mi][ni][reg] + bval);
            }
        }
      }
      __syncthreads();
#pragma unroll
      for (int i = 0; i < 2; i++) {
        int u = i * 256 + tid;
        int cl = u >> 4;
        int rc = u & 15;
        uint4 v = *(const uint4*)&Cs[cl][rc * 8];
        *(uint4*)&Vg[(size_t)(b * 1024 + n0v + p * 32 + cl) * 2048 + s0 + rc * 8] = v;
      }
    }
  }
}

// ---------------------------------------------------------------------------
// Flash attention (round-9 form: BC=64, 6 blocks/CU, swapped-QK^T softmax).
// ---------------------------------------------------------------------------
#define BC 64
__global__ __launch_bounds__(256, 6)
void attn_kernel(const bf16* __restrict__ QKb, const bf16* __restrict__ Vg,
                 const int* __restrict__ mask, bf16* __restrict__ O) {
  __shared__ __attribute__((aligned(16))) bf16 Ks[BC][64];     // [key][d] swz
  __shared__ __attribute__((aligned(16))) bf16 Vt[64][BC];     // [d][key] swz
  __shared__ __attribute__((aligned(16))) bf16 Ps[4][16][72];  // per-wave P
  const int tid = threadIdx.x;
  const int wave = tid >> 6, lane = tid & 63;
  const int pid = blockIdx.x;         // 2048 blocks
  const int xcd = pid & 7;
  const int jj = pid >> 3;            // 0..255
  const int bh = xcd * 8 + (jj >> 5); // 8 bh per XCD
  const int b = bh >> 4, h = bh & 15;
  const int q0 = (jj & 31) * 64;
  const int row_q = lane & 15, quad = lane >> 4;

  bf16x8 qf[2];
  {
    int qrow = q0 + wave * 16 + row_q;
    const bf16* qp = QKb + (size_t)(b * 2048 + qrow) * 2048 + h * 64 + quad * 8;
    qf[0] = *(const bf16x8*)qp;
    qf[1] = *(const bf16x8*)(qp + 32);
#pragma unroll
    for (int ks = 0; ks < 2; ks++)
#pragma unroll
      for (int e = 0; e < 8; e++) qf[ks][e] = f2b(b2f(qf[ks][e]) * 0.125f);
  }
  float m_i = -1e30f, l_i = 0.f;
  const f32x4 fz = {0.f, 0.f, 0.f, 0.f};
  f32x4 o_acc[4];
#pragma unroll
  for (int d = 0; d < 4; d++) o_acc[d] = fz;

  int ki[2], kdc[2], ksc[2];
#pragma unroll
  for (int j = 0; j < 2; j++) {
    int c = j * 256 + tid;
    ki[j] = c >> 3;  kdc[j] = c & 7;
    ksc[j] = (c & 7) ^ (ki[j] & 7);
  }
  const bf16* Kbase = QKb + (size_t)b * 2048 * 2048 + 1024 + h * 64;
  const bf16* Vbase = Vg + (size_t)(b * 1024 + h * 64) * 2048;
  const int* mrow = mask + b * 2048;
  const int swz = row_q & 7;

  unsigned int allmask = 0;
  for (int kb = 0; kb < 2048 / BC; kb++) {
    int mm = mrow[kb * BC + lane];
    if (__ballot(mm != 0) == ~0ull) allmask |= (1u << kb);
  }

  for (int kb = 0; kb < 2048 / BC; kb++) {
    __syncthreads();
#pragma unroll
    for (int j = 0; j < 2; j++)
      GLD16(Kbase + (size_t)(kb * BC + ki[j]) * 2048 + ksc[j] * 8,
            &Ks[ki[j]][kdc[j] * 8]);
#pragma unroll
    for (int j = 0; j < 2; j++)
      GLD16(Vbase + (size_t)ki[j] * 2048 + kb * BC + ksc[j] * 8,
            &Vt[ki[j]][kdc[j] * 8]);
    __syncthreads();

    f32x4 sacc[4];
#pragma unroll
    for (int nt = 0; nt < 4; nt++) sacc[nt] = fz;
#pragma unroll
    for (int ks = 0; ks < 2; ks++) {
      int kcf = ((ks * 4 + quad) ^ swz) * 8;
#pragma unroll
      for (int nt = 0; nt < 4; nt++) {
        bf16x8 kf = *(const bf16x8*)&Ks[nt * 16 + row_q][kcf];
        sacc[nt] = __builtin_amdgcn_mfma_f32_16x16x32_bf16(kf, qf[ks], sacc[nt], 0, 0, 0);
      }
    }
    if (!((allmask >> kb) & 1u)) {
#pragma unroll
      for (int nt = 0; nt < 4; nt++) {
        int4 m4 = *(const int4*)&mrow[kb * BC + nt * 16 + quad * 4];
#pragma unroll
        for (int r = 0; r < 4; r++)
          if (((const int*)&m4)[r] == 0) sacc[nt][r] = -1e9f;
      }
    }
    float mq[4];
#pragma unroll
    for (int nt = 0; nt < 4; nt++)
      mq[nt] = fmaxf(fmaxf(sacc[nt][0], sacc[nt][1]),
                     fmaxf(sacc[nt][2], sacc[nt][3]));
    float mx = fmaxf(fmaxf(mq[0], mq[1]), fmaxf(mq[2], mq[3]));
    mx = fmaxf(mx, __shfl_xor(mx, 16));
    mx = fmaxf(mx, __shfl_xor(mx, 32));
    if (!__all(mx - m_i <= 5.0f)) {
      float mnew = fmaxf(m_i, mx);
      float alpha = __expf(m_i - mnew);
      m_i = mnew;
      l_i *= alpha;
      float al[4];
#pragma unroll
      for (int r = 0; r < 4; r++) al[r] = __shfl(alpha, quad * 4 + r);
#pragma unroll
      for (int d = 0; d < 4; d++)
#pragma unroll
        for (int r = 0; r < 4; r++) o_acc[d][r] *= al[r];
    }
    float rs = 0.f;
#pragma unroll
    for (int nt = 0; nt < 4; nt++) {
      float p0 = __expf(sacc[nt][0] - m_i);
      float p1 = __expf(sacc[nt][1] - m_i);
      float p2 = __expf(sacc[nt][2] - m_i);
      float p3 = __expf(sacc[nt][3] - m_i);
      rs += (p0 + p1) + (p2 + p3);
      bf16x4 pv = {f2b(p0), f2b(p1), f2b(p2), f2b(p3)};
      *(bf16x4*)&Ps[wave][row_q][nt * 16 + quad * 4] = pv;
    }
    rs += __shfl_xor(rs, 16);
    rs += __shfl_xor(rs, 32);
    l_i += rs;
#pragma unroll
    for (int kst = 0; kst < 2; kst++) {
      bf16x8 pf = *(const bf16x8*)&Ps[wave][row_q][kst * 32 + quad * 8];
      int vcf = ((kst * 4 + quad) ^ swz) * 8;
#pragma unroll
      for (int d = 0; d < 4; d++) {
        bf16x8 vf = *(const bf16x8*)&Vt[d * 16 + row_q][vcf];
        o_acc[d] = __builtin_amdgcn_mfma_f32_16x16x32_bf16(pf, vf, o_acc[d], 0, 0, 0);
      }
    }
  }
  float lv[4];
#pragma unroll
  for (int r = 0; r < 4; r++) lv[r] = __shfl(l_i, quad * 4 + r);
#pragma unroll
  for (int d = 0; d < 4; d++) {
#pragma unroll
    for (int r = 0; r < 4; r++) {
      int row = q0 + wave * 16 + quad * 4 + r;
      float v = o_acc[d][r] / fmaxf(lv[r], 1e-20f);
      O[(size_t)(b * 2048 + row) * 1024 + h * 64 + d * 16 + row_q] = f2b(v);
    }
  }
}

// ---------------------------------------------------------------------------
// Residual + LayerNorm (bf16 out), vectorized.
// ---------------------------------------------------------------------------
__global__ __launch_bounds__(256)
void ln_kernel(const bf16* __restrict__ a, const bf16* __restrict__ res,
               const bf16* __restrict__ g, const bf16* __restrict__ be,
               bf16* __restrict__ out) {
  const int tid = threadIdx.x;
  __shared__ float red[8];
  const size_t base = (size_t)blockIdx.x * 1024;
  bf16x4 av = *(const bf16x4*)&a[base + tid * 4];
  bf16x4 rv = *(const bf16x4*)&res[base + tid * 4];
  float xs[4], sum = 0.f, sq = 0.f;
#pragma unroll
  for (int i = 0; i < 4; i++) {
    float x = b2f(av[i]) + b2f(rv[i]);
    xs[i] = x; sum += x; sq += x * x;
  }
#pragma unroll
  for (int off = 1; off < 64; off <<= 1) {
    sum += __shfl_xor(sum, off);
    sq += __shfl_xor(sq, off);
  }
  int wave = tid >> 6, lane = tid & 63;
  if (lane == 0) { red[wave] = sum; red[4 + wave] = sq; }
  __syncthreads();
  sum = red[0] + red[1] + red[2] + red[3];
  sq = red[4] + red[5] + red[6] + red[7];
  float mu = sum * (1.f / 1024.f);
  float var = sq * (1.f / 1024.f) - mu * mu;
  float rstd = rsqrtf(fmaxf(var, 0.f) + 1e-5f);
  bf16x4 gv = *(const bf16x4*)&g[tid * 4];
  bf16x4 bv = *(const bf16x4*)&be[tid * 4];
  bf16x4 ov;
#pragma unroll
  for (int i = 0; i < 4; i++)
    ov[i] = f2b((xs[i] - mu) * rstd * b2f(gv[i]) + b2f(bv[i]));
  *(bf16x4*)&out[base + tid * 4] = ov;
}

// Final LN: writes fp32 or bf16 per flag; vectorized.
__global__ __launch_bounds__(256)
void ln_out_kernel(const bf16* __restrict__ a, const bf16* __restrict__ res,
                   const bf16* __restrict__ g, const bf16* __restrict__ be,
                   void* __restrict__ out, const int* __restrict__ flag) {
  const int f = *flag;
  const int tid = threadIdx.x;
  __shared__ float red[8];
  const size_t base = (size_t)blockIdx.x * 1024;
  bf16x4 av = *(const bf16x4*)&a[base + tid * 4];
  bf16x4 rv = *(const bf16x4*)&res[base + tid * 4];
  float xs[4], sum = 0.f, sq = 0.f;
#pragma unroll
  for (int i = 0; i < 4; i++) {
    float x = b2f(av[i]) + b2f(rv[i]);
    xs[i] = x; sum += x; sq += x * x;
  }
#pragma unroll
  for (int off = 1; off < 64; off <<= 1) {
    sum += __shfl_xor(sum, off);
    sq += __shfl_xor(sq, off);
  }
  int wave = tid >> 6, lane = tid & 63;
  if (lane == 0) { red[wave] = sum; red[4 + wave] = sq; }
  __syncthreads();
  sum = red[0] + red[1] + red[2] + red[3];
  sq = red[4] + red[5] + red[6] + red[7];
  float mu = sum * (1.f / 1024.f);
  float var = sq * (1.f / 1024.f) - mu * mu;
  float rstd = rsqrtf(fmaxf(var, 0.f) + 1e-5f);
  bf16x4 gv = *(const bf16x4*)&g[tid * 4];
  bf16x4 bv = *(const bf16x4*)&be[tid * 4];
  float y[4];
#pragma unroll
  for (int i = 0; i < 4; i++)
    y[i] = (xs[i] - mu) * rstd * b2f(gv[i]) + b2f(bv[i]);
  if (f) {
    float4 o = {y[0], y[1], y[2], y[3]};
    ((float4*)out)[base / 4 + tid] = o;
  } else {
    bf16x4 o = {f2b(y[0]), f2b(y[1]), f2b(y[2]), f2b(y[3])};
    *(bf16x4*)&((bf16*)out)[base + tid * 4] = o;
  }
}

// ---------------------------------------------------------------------------
extern "C" void kernel_launch(void* const* d_in, const int* in_sizes, int n_in,
                              void* d_out, int out_size, void* d_ws, size_t ws_size,
                              hipStream_t stream) {
  (void)in_sizes; (void)n_in; (void)out_size; (void)ws_size;
  const void* x   = d_in[0];
  const int* mask = (const int*)d_in[1];
  const void* Wq  = d_in[2];
  const void* bq  = d_in[3];
  const void* Wk  = d_in[4];
  const void* bk  = d_in[5];
  const void* Wv  = d_in[6];
  const void* bv  = d_in[7];
  const void* Wo  = d_in[8];
  const void* bo  = d_in[9];
  const void* W1  = d_in[10];
  const void* b1  = d_in[11];
  const void* W2  = d_in[12];
  const void* b2  = d_in[13];
  const void* g1  = d_in[14];
  const void* be1 = d_in[15];
  const void* g2  = d_in[16];
  const void* be2 = d_in[17];

  // workspace layout (125,861,888 B total)
  char* ws = (char*)d_ws;
  bf16* xb    = (bf16*)(ws + 0);            // 16,777,216  [8192][1024]
  bf16* WqkvT = (bf16*)(ws + 16777216);     //  6,291,456  [3072][1024]
  bf16* WoT   = (bf16*)(ws + 23068672);     //  2,097,152  [1024][1024]
  bf16* W1T   = (bf16*)(ws + 25165824);     //  8,388,608  [4096][1024]
  bf16* W2T   = (bf16*)(ws + 33554432);     //  8,388,608  [1024][4096]
  bf16* sv    = (bf16*)(ws + 41943040);     // small-vector arena
  bf16* bqkvB = sv;                         // 3072
  bf16* boB   = sv + 3072;                  // 1024
  bf16* b1B   = sv + 4096;                  // 4096
  bf16* b2B   = sv + 8192;                  // 1024
  bf16* g1B   = sv + 9216;                  // 1024
  bf16* be1B  = sv + 10240;                 // 1024
  bf16* g2B   = sv + 11264;                 // 1024
  bf16* be2B  = sv + 12288;                 // 1024
  int*  flag  = (int*)(ws + 41943040 + 26624);
  bf16* QKb   = (bf16*)(ws + 41975808);     // 33,554,432  [8192][2048]
  bf16* Vg    = (bf16*)(ws + 75530240);     // 16,777,216  [4096][2048] d-major
  bf16* Obuf  = (bf16*)(ws + 92307456);     // 16,777,216  [8192][1024]
  bf16* hbuf  = (bf16*)(ws + 109084672);    // 16,777,216  [8192][1024]
  bf16* attnp = (bf16*)(ws + 41975808);     // reuses QKb (dead after attn)
  bf16* ff1   = (bf16*)(ws + 41975808);     // 67,108,864  reuses QKb+Vg+Obuf
  bf16* ff2o  = (bf16*)(ws + 0);            // reuses xb (dead after LN1)

  sniff_kernel<<<1, 256, 0, stream>>>(x, flag);

  cvt_kernel8<<<4096, 256, 0, stream>>>(x, xb, 1048576, flag);
  cvt_biases_kernel<<<52, 256, 0, stream>>>(bq, bk, bv, bo, b1, b2, g1, be1,
                                            g2, be2, sv, flag);

  dim3 tb(32, 8);
  transpose_all<<<12288, tb, 0, stream>>>(Wq, Wk, Wv, Wo, W1, W2,
                                          WqkvT, WoT, W1T, W2T, flag);

  // merged QKV projection (N=3072; Q|K -> QKb, V -> Vg transposed)
  gemm_qkv<8><<<1536, 256, 0, stream>>>(xb, WqkvT, bqkvB, QKb, Vg, 8192, 1024);
  attn_kernel<<<2048, 256, 0, stream>>>(QKb, Vg, mask, Obuf);
  gemm_bt<0, 8><<<512, 256, 0, stream>>>(Obuf, WoT, boB, attnp, 8192, 1024, 1024);
  ln_kernel<<<8192, 256, 0, stream>>>(xb, attnp, g1B, be1B, hbuf);
  gemm_bt<1, 8><<<2048, 256, 0, stream>>>(hbuf, W1T, b1B, ff1, 8192, 4096, 1024);
  gemm_bt<0, 4><<<512, 256, 0, stream>>>(ff1, W2T, b2B, ff2o, 8192, 1024, 4096);
  ln_out_kernel<<<8192, 256, 0, stream>>>(hbuf, ff2o, g2B, be2B, d_out, flag);
}